// Round 1
// baseline (479.183 us; speedup 1.0000x reference)
//
#include <hip/hip_runtime.h>
#include <math.h>

// Problem constants (B, C, H, W) = (8, 512, 32, 32)
#define B_    8
#define C_    512
#define HW_   1024
#define O3_   1536     // 3*C
#define HEADS_ 8
#define D_    64       // head dim
#define G_    32       // groups
#define CPG_  16       // channels per group
#define EPS_  1e-5f

typedef __bf16 bf16x8 __attribute__((ext_vector_type(8)));
typedef float  f32x4  __attribute__((ext_vector_type(4)));

// ---------------------------------------------------------------------------
// Kernel 1: GroupNorm. One block per (b, g). Computes mean/var over 16 ch x
// 1024 spatial, then writes normalized+affine result as bf16 TRANSPOSED to
// h[b][hw][c] so downstream MFMA A-fragments are contiguous.
// ---------------------------------------------------------------------------
__global__ __launch_bounds__(256) void k_gn(const float* __restrict__ x,
                                            const float* __restrict__ gw,
                                            const float* __restrict__ gb,
                                            __bf16* __restrict__ h) {
  int bg = blockIdx.x;
  int b = bg >> 5, g = bg & 31;
  const float* xg = x + ((size_t)(b * C_) + g * CPG_) * HW_;
  int tid = threadIdx.x;

  // pass 1: coalesced reads (hw fastest)
  float s = 0.f, ss = 0.f;
  for (int i = tid; i < CPG_ * HW_; i += 256) {
    float v = xg[(i >> 10) * HW_ + (i & 1023)];
    s += v; ss += v * v;
  }
  for (int off = 32; off > 0; off >>= 1) {
    s  += __shfl_down(s, off, 64);
    ss += __shfl_down(ss, off, 64);
  }
  __shared__ float red[10];
  int wv = tid >> 6;
  if ((tid & 63) == 0) { red[wv] = s; red[4 + wv] = ss; }
  __syncthreads();
  if (tid == 0) {
    float S  = red[0] + red[1] + red[2] + red[3];
    float SS = red[4] + red[5] + red[6] + red[7];
    float mean = S / (float)(CPG_ * HW_);
    float var  = SS / (float)(CPG_ * HW_) - mean * mean;
    red[8] = mean;
    red[9] = rsqrtf(var + EPS_);
  }
  __syncthreads();
  float mean = red[8], rstd = red[9];

  // pass 2: c-minor arrangement -> 32B-contiguous bf16 writes per 16 lanes
  int c_l = tid & 15;
  float gamma = gw[g * CPG_ + c_l], beta = gb[g * CPG_ + c_l];
  __bf16* hb = h + (size_t)b * HW_ * C_ + g * CPG_ + c_l;
  for (int i = tid; i < CPG_ * HW_; i += 256) {
    int hw = i >> 4;
    float v = xg[c_l * HW_ + hw];          // L1/L2-hot from pass 1
    float yv = (v - mean) * rstd * gamma + beta;
    hb[(size_t)hw * C_] = (__bf16)yv;
  }
}

// ---------------------------------------------------------------------------
// Kernel 2: weight fp32 -> bf16 (both qkv_w and proj_w)
// ---------------------------------------------------------------------------
__global__ __launch_bounds__(256) void k_cvt(const float* __restrict__ qw,
                                             const float* __restrict__ pw,
                                             __bf16* __restrict__ qwb,
                                             __bf16* __restrict__ pwb) {
  int i = blockIdx.x * 256 + threadIdx.x;
  if (i < O3_ * C_) qwb[i] = (__bf16)qw[i];
  if (i < C_ * C_)  pwb[i] = (__bf16)pw[i];
}

// ---------------------------------------------------------------------------
// Kernel 3: QKV GEMM. y[b][hw][o] = sum_c h[b][hw][c] * w[o][c] + bias[o].
// Per-wave 16x16 tile; mfma_f32_16x16x32_bf16; both fragments are contiguous
// 16B loads (h is hw-major, w is o-row-major over c).
// grid (64 hw-tiles, 24 o-tile-groups, 8 b), block 256 (4 waves).
// ---------------------------------------------------------------------------
__global__ __launch_bounds__(256) void k_qkv(const __bf16* __restrict__ h,
                                             const __bf16* __restrict__ w,
                                             const float* __restrict__ bias,
                                             __bf16* __restrict__ y) {
  int b = blockIdx.z;
  int hw0 = blockIdx.x * 16;
  int wv = threadIdx.x >> 6;
  int o0 = (blockIdx.y * 4 + wv) * 16;
  int lane = threadIdx.x & 63;
  int l16 = lane & 15, quad = lane >> 4;

  const __bf16* arow = h + (size_t)(b * HW_ + hw0 + l16) * C_ + quad * 8;
  const __bf16* brow = w + (size_t)(o0 + l16) * C_ + quad * 8;
  f32x4 acc = {0.f, 0.f, 0.f, 0.f};
#pragma unroll
  for (int k = 0; k < C_; k += 32) {
    bf16x8 a  = *(const bf16x8*)(arow + k);
    bf16x8 bb = *(const bf16x8*)(brow + k);
    acc = __builtin_amdgcn_mfma_f32_16x16x32_bf16(a, bb, acc, 0, 0, 0);
  }
  int o = o0 + l16;
  float bv = bias[o];
#pragma unroll
  for (int r = 0; r < 4; r++) {
    int hw = hw0 + quad * 4 + r;           // D row = (lane>>4)*4 + reg
    y[(size_t)(b * HW_ + hw) * O3_ + o] = (__bf16)(acc[r] + bv);
  }
}

// ---------------------------------------------------------------------------
// Kernel 4: attention, flash-style online softmax.
// grid (16 q-tiles, 8 heads, 8 b), block 256 = 4 waves, wave owns 16 q rows.
// q/k/v are slices of y: q at o=h*64, k at o=512+h*64, v at o=1024+h*64.
// ---------------------------------------------------------------------------
__global__ __launch_bounds__(256) void k_attn(const __bf16* __restrict__ y,
                                              __bf16* __restrict__ ao) {
  int b = blockIdx.z, hd = blockIdx.y, qt = blockIdx.x;
  int wv = threadIdx.x >> 6, lane = threadIdx.x & 63;
  int l16 = lane & 15, quad = lane >> 4;
  int q0 = qt * 64 + wv * 16;

  const __bf16* qbase = y + (size_t)(b * HW_) * O3_ + hd * D_;
  const __bf16* kbase = qbase + C_;        // K block
  const __bf16* vbase = qbase + 2 * C_;    // V block

  // Q A-fragments: A[m=lane&15][k=quad*8+j], two K=32 halves of d=64
  const __bf16* qrow = qbase + (size_t)(q0 + l16) * O3_ + quad * 8;
  bf16x8 qa0 = *(const bf16x8*)(qrow);
  bf16x8 qa1 = *(const bf16x8*)(qrow + 32);

  float m_run[4], l_run[4];
  f32x4 o_acc[4];
#pragma unroll
  for (int r = 0; r < 4; r++) { m_run[r] = -INFINITY; l_run[r] = 0.f; }
#pragma unroll
  for (int dt = 0; dt < 4; dt++) o_acc[dt] = f32x4{0.f, 0.f, 0.f, 0.f};

  __shared__ __bf16 Ps[4][16][32];   // per-wave P staging (C-layout -> A-layout)

  for (int kt = 0; kt < HW_; kt += 32) {
    // ---- S = Q * K^T for 16q x 32k tile (2 column-halves) ----
    f32x4 s0 = {0.f, 0.f, 0.f, 0.f}, s1 = {0.f, 0.f, 0.f, 0.f};
    {
      const __bf16* kr0 = kbase + (size_t)(kt + l16) * O3_ + quad * 8;
      bf16x8 kb0a = *(const bf16x8*)(kr0);
      bf16x8 kb0b = *(const bf16x8*)(kr0 + 32);
      s0 = __builtin_amdgcn_mfma_f32_16x16x32_bf16(qa0, kb0a, s0, 0, 0, 0);
      s0 = __builtin_amdgcn_mfma_f32_16x16x32_bf16(qa1, kb0b, s0, 0, 0, 0);
      const __bf16* kr1 = kbase + (size_t)(kt + 16 + l16) * O3_ + quad * 8;
      bf16x8 kb1a = *(const bf16x8*)(kr1);
      bf16x8 kb1b = *(const bf16x8*)(kr1 + 32);
      s1 = __builtin_amdgcn_mfma_f32_16x16x32_bf16(qa0, kb1a, s1, 0, 0, 0);
      s1 = __builtin_amdgcn_mfma_f32_16x16x32_bf16(qa1, kb1b, s1, 0, 0, 0);
    }

    // ---- online softmax: row r lives in the 16 lanes of this quad ----
    float al[4];
#pragma unroll
    for (int r = 0; r < 4; r++) {
      float v0 = s0[r] * 0.125f;           // scale = d^-0.5 = 1/8
      float v1 = s1[r] * 0.125f;
      float t = fmaxf(v0, v1);
#pragma unroll
      for (int off = 8; off > 0; off >>= 1) t = fmaxf(t, __shfl_xor(t, off, 16));
      float mnew = fmaxf(m_run[r], t);
      float a = __expf(m_run[r] - mnew);
      m_run[r] = mnew;
      float p0 = __expf(v0 - mnew);
      float p1 = __expf(v1 - mnew);
      float rs = p0 + p1;
#pragma unroll
      for (int off = 8; off > 0; off >>= 1) rs += __shfl_xor(rs, off, 16);
      l_run[r] = l_run[r] * a + rs;
      al[r] = a;
      s0[r] = p0; s1[r] = p1;
    }
#pragma unroll
    for (int dt = 0; dt < 4; dt++)
#pragma unroll
      for (int r = 0; r < 4; r++) o_acc[dt][r] *= al[r];

    // ---- P: C-layout -> LDS -> A-layout ----
#pragma unroll
    for (int r = 0; r < 4; r++) {
      Ps[wv][quad * 4 + r][l16]      = (__bf16)s0[r];
      Ps[wv][quad * 4 + r][16 + l16] = (__bf16)s1[r];
    }
    __syncthreads();
    bf16x8 pa = *(const bf16x8*)(&Ps[wv][l16][quad * 8]);

    // ---- O += P * V : B[k=ki][n=d] read direct from global (L2-hot) ----
#pragma unroll
    for (int dt = 0; dt < 4; dt++) {
      bf16x8 vb;
#pragma unroll
      for (int j = 0; j < 8; j++)
        vb[j] = vbase[(size_t)(kt + quad * 8 + j) * O3_ + dt * 16 + l16];
      o_acc[dt] = __builtin_amdgcn_mfma_f32_16x16x32_bf16(pa, vb, o_acc[dt], 0, 0, 0);
    }
  }

  // epilogue: ao[b][hw=q][h*64+d] bf16, divide by running sum
#pragma unroll
  for (int dt = 0; dt < 4; dt++) {
#pragma unroll
    for (int r = 0; r < 4; r++) {
      float val = o_acc[dt][r] / l_run[r];
      int qg = q0 + quad * 4 + r;
      ao[(size_t)(b * HW_ + qg) * C_ + hd * D_ + dt * 16 + l16] = (__bf16)val;
    }
  }
}

// ---------------------------------------------------------------------------
// Kernel 5: proj GEMM + bias + residual. out[b][o][hw] fp32 (reference layout)
// grid (64 hw-tiles, 8 o-tile-groups, 8 b), block 256 (4 waves).
// ---------------------------------------------------------------------------
__global__ __launch_bounds__(256) void k_proj(const __bf16* __restrict__ ao,
                                              const __bf16* __restrict__ w,
                                              const float* __restrict__ bias,
                                              const float* __restrict__ x,
                                              float* __restrict__ out) {
  int b = blockIdx.z;
  int hw0 = blockIdx.x * 16;
  int wv = threadIdx.x >> 6;
  int o0 = (blockIdx.y * 4 + wv) * 16;
  int lane = threadIdx.x & 63;
  int l16 = lane & 15, quad = lane >> 4;

  const __bf16* arow = ao + (size_t)(b * HW_ + hw0 + l16) * C_ + quad * 8;
  const __bf16* brow = w + (size_t)(o0 + l16) * C_ + quad * 8;
  f32x4 acc = {0.f, 0.f, 0.f, 0.f};
#pragma unroll
  for (int k = 0; k < C_; k += 32) {
    bf16x8 a  = *(const bf16x8*)(arow + k);
    bf16x8 bb = *(const bf16x8*)(brow + k);
    acc = __builtin_amdgcn_mfma_f32_16x16x32_bf16(a, bb, acc, 0, 0, 0);
  }
  int o = o0 + l16;
  float bv = bias[o];
  int hw = hw0 + quad * 4;                 // 4 consecutive rows per lane
  size_t oidx = (size_t)(b * C_ + o) * HW_ + hw;
  float4 xr = *(const float4*)(x + oidx);
  float4 res;
  res.x = acc[0] + bv + xr.x;
  res.y = acc[1] + bv + xr.y;
  res.z = acc[2] + bv + xr.z;
  res.w = acc[3] + bv + xr.w;
  *(float4*)(out + oidx) = res;
}

// ---------------------------------------------------------------------------
extern "C" void kernel_launch(void* const* d_in, const int* in_sizes, int n_in,
                              void* d_out, int out_size, void* d_ws, size_t ws_size,
                              hipStream_t stream) {
  const float* x      = (const float*)d_in[0];
  const float* gn_w   = (const float*)d_in[1];
  const float* gn_b   = (const float*)d_in[2];
  const float* qkv_w  = (const float*)d_in[3];
  const float* qkv_b  = (const float*)d_in[4];
  const float* proj_w = (const float*)d_in[5];
  const float* proj_b = (const float*)d_in[6];
  float* out = (float*)d_out;

  char* ws = (char*)d_ws;
  // workspace layout (bytes):
  //   h    : B*HW*C  bf16 =  8,388,608
  //   qwb  : 1536*512 bf16 = 1,572,864
  //   pwb  : 512*512  bf16 =   524,288
  //   y    : B*HW*1536 bf16 = 25,165,824
  //   ao   : B*HW*C  bf16 =  8,388,608   (total ~42 MB)
  __bf16* h   = (__bf16*)(ws);
  __bf16* qwb = (__bf16*)(ws + 8388608);
  __bf16* pwb = (__bf16*)(ws + 8388608 + 1572864);
  __bf16* yq  = (__bf16*)(ws + 8388608 + 1572864 + 524288);
  __bf16* ao  = (__bf16*)(ws + 8388608 + 1572864 + 524288 + 25165824);

  k_gn  <<<B_ * G_, 256, 0, stream>>>(x, gn_w, gn_b, h);
  k_cvt <<<(O3_ * C_ + 255) / 256, 256, 0, stream>>>(qkv_w, proj_w, qwb, pwb);
  k_qkv <<<dim3(HW_ / 16, 24, B_), 256, 0, stream>>>(h, qwb, qkv_b, yq);
  k_attn<<<dim3(16, HEADS_, B_), 256, 0, stream>>>(yq, ao);
  k_proj<<<dim3(HW_ / 16, 8, B_), 256, 0, stream>>>(ao, pwb, proj_b, x, out);
  (void)in_sizes; (void)n_in; (void)out_size; (void)ws_size;
}

// Round 2
// 234.324 us; speedup vs baseline: 2.0450x; 2.0450x over previous
//
#include <hip/hip_runtime.h>
#include <math.h>

// Problem constants (B, C, H, W) = (8, 512, 32, 32)
#define B_    8
#define C_    512
#define HW_   1024
#define O3_   1536     // 3*C
#define HEADS_ 8
#define D_    64       // head dim
#define G_    32       // groups
#define CPG_  16       // channels per group
#define EPS_  1e-5f
#define M_TOT 8192     // B*HW

typedef __bf16 bf16x8 __attribute__((ext_vector_type(8)));
typedef __bf16 bf16x4 __attribute__((ext_vector_type(4)));
typedef float  f32x4  __attribute__((ext_vector_type(4)));

// async global->LDS, 16B per lane (wave-uniform base + lane*16 layout)
__device__ __forceinline__ void async_copy16(void* lds, const void* g) {
  __builtin_amdgcn_global_load_lds(
      (const __attribute__((address_space(1))) unsigned int*)g,
      (__attribute__((address_space(3))) unsigned int*)lds, 16, 0, 0);
}

// ---------------------------------------------------------------------------
// Kernel 1: GroupNorm -> bf16, transposed to h[b][hw][c].
// One block per (b,g). All global reads coalesced; transpose via LDS tile
// (stride 1030 breaks the 16-way column-read bank conflict).
// ---------------------------------------------------------------------------
__global__ __launch_bounds__(256) void k_gn(const float* __restrict__ x,
                                            const float* __restrict__ gw,
                                            const float* __restrict__ gb,
                                            __bf16* __restrict__ h) {
  __shared__ float red[10];
  __shared__ __bf16 T[16 * 1030];
  int bg = blockIdx.x;
  int b = bg >> 5, g = bg & 31;
  const float* xg = x + ((size_t)(b * C_) + g * CPG_) * HW_;
  int tid = threadIdx.x;

  // pass 1: coalesced, sum + sumsq
  float s = 0.f, ss = 0.f;
  for (int i = tid; i < CPG_ * HW_; i += 256) {
    float v = xg[i];
    s += v; ss += v * v;
  }
  for (int off = 32; off > 0; off >>= 1) {
    s  += __shfl_down(s, off, 64);
    ss += __shfl_down(ss, off, 64);
  }
  int wv = tid >> 6;
  if ((tid & 63) == 0) { red[wv] = s; red[4 + wv] = ss; }
  __syncthreads();
  if (tid == 0) {
    float S  = red[0] + red[1] + red[2] + red[3];
    float SS = red[4] + red[5] + red[6] + red[7];
    float mean = S / (float)(CPG_ * HW_);
    float var  = SS / (float)(CPG_ * HW_) - mean * mean;
    red[8] = mean;
    red[9] = rsqrtf(var + EPS_);
  }
  __syncthreads();
  float mean = red[8], rstd = red[9];

  // pass 2: coalesced read again (L2-hot), normalize, stage into T[c][hw]
  for (int i = tid; i < CPG_ * HW_; i += 256) {
    int c = i >> 10, hw = i & 1023;          // c is block-uniform per iter
    float ga = gw[g * CPG_ + c], be = gb[g * CPG_ + c];
    float v = xg[i];
    T[c * 1030 + hw] = (__bf16)((v - mean) * rstd * ga + be);
  }
  __syncthreads();

  // pass 3: write h[b][hw][g*16+c]; LDS column reads conflict-free (stride 1030)
  __bf16* hb = h + (size_t)b * HW_ * C_ + g * CPG_;
  for (int j = tid; j < CPG_ * HW_; j += 256) {
    int hw = j >> 4, c = j & 15;
    hb[(size_t)hw * C_ + c] = T[c * 1030 + hw];
  }
}

// ---------------------------------------------------------------------------
// Kernel 2: weight fp32 -> bf16 (both qkv_w and proj_w)
// ---------------------------------------------------------------------------
__global__ __launch_bounds__(256) void k_cvt(const float* __restrict__ qw,
                                             const float* __restrict__ pw,
                                             __bf16* __restrict__ qwb,
                                             __bf16* __restrict__ pwb) {
  int i = blockIdx.x * 256 + threadIdx.x;
  if (i < O3_ * C_) qwb[i] = (__bf16)qw[i];
  if (i < C_ * C_)  pwb[i] = (__bf16)pw[i];
}

// ---------------------------------------------------------------------------
// Shared 128x128-tile GEMM core (m97 structure): C[m][n] = A[m][:]·B[n][:]
// (both operands row-major over K=512). 256 threads / 4 waves, each wave a
// 64x64 quadrant = 4x4 MFMA 16x16x32 tiles. LDS staged via global_load_lds
// width-16 (unpadded [128][32] layout, required by wave-uniform dest rule).
// ---------------------------------------------------------------------------
#define BK 32
__device__ __forceinline__ void gemm128_core(const __bf16* __restrict__ aBase,
                                             const __bf16* __restrict__ bBase,
                                             __bf16* As, __bf16* Bs,
                                             f32x4 acc[4][4]) {
  int t = threadIdx.x;
  int lane = t & 63;
  int l16 = lane & 15, quad = lane >> 4;
  int wv = t >> 6;
  int wm = (wv >> 1) * 64, wn = (wv & 1) * 64;

  int srow = t >> 2, scol = (t & 3) * 8;   // staging: 16B chunk per thread x2
  const __bf16* ag0 = aBase + (size_t)srow * C_ + scol;
  const __bf16* ag1 = aBase + (size_t)(srow + 64) * C_ + scol;
  const __bf16* bg0 = bBase + (size_t)srow * C_ + scol;
  const __bf16* bg1 = bBase + (size_t)(srow + 64) * C_ + scol;
  __bf16* lA0 = As + t * 8;
  __bf16* lA1 = As + t * 8 + 2048;
  __bf16* lB0 = Bs + t * 8;
  __bf16* lB1 = Bs + t * 8 + 2048;

  for (int k0 = 0; k0 < C_; k0 += BK) {
    async_copy16(lA0, ag0 + k0);
    async_copy16(lA1, ag1 + k0);
    async_copy16(lB0, bg0 + k0);
    async_copy16(lB1, bg1 + k0);
    __syncthreads();                        // drains vmcnt (incl. lds loads)
    bf16x8 af[4], bf[4];
#pragma unroll
    for (int i = 0; i < 4; i++) {
      af[i] = *(const bf16x8*)(As + (wm + i * 16 + l16) * BK + quad * 8);
      bf[i] = *(const bf16x8*)(Bs + (wn + i * 16 + l16) * BK + quad * 8);
    }
#pragma unroll
    for (int i = 0; i < 4; i++)
#pragma unroll
      for (int j = 0; j < 4; j++)
        acc[i][j] = __builtin_amdgcn_mfma_f32_16x16x32_bf16(af[i], bf[j],
                                                            acc[i][j], 0, 0, 0);
    __syncthreads();                        // reads done before next overwrite
  }
}

// Kernel 3: QKV GEMM. A = h[8192][512], B = qkv_w[1536][512].
// y[m][n] bf16, n-coalesced stores. grid (64 m-tiles, 12 n-tiles).
__global__ __launch_bounds__(256) void k_qkv(const __bf16* __restrict__ h,
                                             const __bf16* __restrict__ w,
                                             const float* __restrict__ bias,
                                             __bf16* __restrict__ y) {
  __shared__ __align__(16) __bf16 As[128 * BK];
  __shared__ __align__(16) __bf16 Bs[128 * BK];
  int m0 = blockIdx.x * 128, n0 = blockIdx.y * 128;
  f32x4 acc[4][4];
#pragma unroll
  for (int i = 0; i < 4; i++)
#pragma unroll
    for (int j = 0; j < 4; j++) acc[i][j] = f32x4{0.f, 0.f, 0.f, 0.f};
  gemm128_core(h + (size_t)m0 * C_, w + (size_t)n0 * C_, As, Bs, acc);

  int lane = threadIdx.x & 63, wv = threadIdx.x >> 6;
  int l16 = lane & 15, quad = lane >> 4;
  int wm = (wv >> 1) * 64, wn = (wv & 1) * 64;
#pragma unroll
  for (int j = 0; j < 4; j++) {
    int n = n0 + wn + j * 16 + l16;
    float bv = bias[n];
#pragma unroll
    for (int i = 0; i < 4; i++)
#pragma unroll
      for (int r = 0; r < 4; r++) {
        int m = m0 + wm + i * 16 + quad * 4 + r;
        y[(size_t)m * O3_ + n] = (__bf16)(acc[i][j][r] + bv);
      }
  }
}

// Kernel 5: proj GEMM + bias + residual, out fp32 [b][o][hw].
// A = proj_w[512][512] (M=o), B = ao[8192][512] (N=token) so stores are
// hw-coalesced (col = lane&15 = token). grid (64 n-tiles, 4 m-tiles).
__global__ __launch_bounds__(256) void k_proj(const __bf16* __restrict__ ao,
                                              const __bf16* __restrict__ w,
                                              const float* __restrict__ bias,
                                              const float* __restrict__ x,
                                              float* __restrict__ out) {
  __shared__ __align__(16) __bf16 As[128 * BK];
  __shared__ __align__(16) __bf16 Bs[128 * BK];
  int n0 = blockIdx.x * 128, m0 = blockIdx.y * 128;  // m = o, n = token
  f32x4 acc[4][4];
#pragma unroll
  for (int i = 0; i < 4; i++)
#pragma unroll
    for (int j = 0; j < 4; j++) acc[i][j] = f32x4{0.f, 0.f, 0.f, 0.f};
  gemm128_core(w + (size_t)m0 * C_, ao + (size_t)n0 * C_, As, Bs, acc);

  int lane = threadIdx.x & 63, wv = threadIdx.x >> 6;
  int l16 = lane & 15, quad = lane >> 4;
  int wm = (wv >> 1) * 64, wn = (wv & 1) * 64;
#pragma unroll
  for (int i = 0; i < 4; i++)
#pragma unroll
    for (int r = 0; r < 4; r++) {
      int o = m0 + wm + i * 16 + quad * 4 + r;
      float bv = bias[o];
#pragma unroll
      for (int j = 0; j < 4; j++) {
        int n = n0 + wn + j * 16 + l16;       // global token index
        int b = n >> 10, hw = n & 1023;
        size_t idx = ((size_t)(b * C_ + o)) * HW_ + hw;
        out[idx] = acc[i][j][r] + bv + x[idx];
      }
    }
}

// ---------------------------------------------------------------------------
// Kernel 4: flash attention. Block = (b, head, 64-q-tile), 4 waves x 16 q.
// K-tile (32x64) and V-tile (transposed, 64x32) staged in LDS per step,
// shared by all waves. Pads: Ks stride 72 (2-way/free), Vt stride 44.
// ---------------------------------------------------------------------------
__global__ __launch_bounds__(256) void k_attn(const __bf16* __restrict__ y,
                                              __bf16* __restrict__ ao) {
  __shared__ __align__(16) __bf16 Ks[32 * 72];   // [token][d]
  __shared__ __align__(16) __bf16 Vt[64 * 44];   // [d][token]
  __shared__ __align__(16) __bf16 Ps[4][16 * 32];
  int b = blockIdx.z, hd = blockIdx.y, qt = blockIdx.x;
  int t = threadIdx.x;
  int wv = t >> 6, lane = t & 63, l16 = lane & 15, quad = lane >> 4;
  int q0 = qt * 64 + wv * 16;

  const __bf16* base = y + (size_t)(b * HW_) * O3_ + hd * D_;
  const __bf16* kg = base + C_;
  const __bf16* vg = base + 2 * C_;

  // Q fragments (held in registers for the whole pass)
  const __bf16* qrow = base + (size_t)(q0 + l16) * O3_ + quad * 8;
  bf16x8 qa0 = *(const bf16x8*)(qrow);
  bf16x8 qa1 = *(const bf16x8*)(qrow + 32);

  // staging assignment: thread covers token t>>3, d-chunk (t&7)*8
  int stok = t >> 3, sd0 = (t & 7) * 8;
  const __bf16* kgs = kg + (size_t)stok * O3_ + sd0;
  const __bf16* vgs = vg + (size_t)stok * O3_ + sd0;

  float m_run[4], l_run[4];
  f32x4 o_acc[4];
#pragma unroll
  for (int r = 0; r < 4; r++) { m_run[r] = -INFINITY; l_run[r] = 0.f; }
#pragma unroll
  for (int dt = 0; dt < 4; dt++) o_acc[dt] = f32x4{0.f, 0.f, 0.f, 0.f};

  for (int kt = 0; kt < HW_; kt += 32) {
    // ---- cooperative staging ----
    bf16x8 kv = *(const bf16x8*)(kgs + (size_t)kt * O3_);
    bf16x8 vv = *(const bf16x8*)(vgs + (size_t)kt * O3_);
    *(bf16x8*)(&Ks[stok * 72 + sd0]) = kv;
#pragma unroll
    for (int j = 0; j < 8; j++) Vt[(sd0 + j) * 44 + stok] = vv[j];
    __syncthreads();

    // ---- S = Q K^T (16q x 32k), two column halves ----
    f32x4 s0 = {0.f, 0.f, 0.f, 0.f}, s1 = {0.f, 0.f, 0.f, 0.f};
    {
      bf16x8 k0a = *(const bf16x8*)(&Ks[l16 * 72 + quad * 8]);
      bf16x8 k0b = *(const bf16x8*)(&Ks[l16 * 72 + 32 + quad * 8]);
      bf16x8 k1a = *(const bf16x8*)(&Ks[(16 + l16) * 72 + quad * 8]);
      bf16x8 k1b = *(const bf16x8*)(&Ks[(16 + l16) * 72 + 32 + quad * 8]);
      s0 = __builtin_amdgcn_mfma_f32_16x16x32_bf16(qa0, k0a, s0, 0, 0, 0);
      s0 = __builtin_amdgcn_mfma_f32_16x16x32_bf16(qa1, k0b, s0, 0, 0, 0);
      s1 = __builtin_amdgcn_mfma_f32_16x16x32_bf16(qa0, k1a, s1, 0, 0, 0);
      s1 = __builtin_amdgcn_mfma_f32_16x16x32_bf16(qa1, k1b, s1, 0, 0, 0);
    }

    // ---- online softmax (row r lives in the 16 lanes of this quad) ----
    float al[4];
#pragma unroll
    for (int r = 0; r < 4; r++) {
      float v0 = s0[r] * 0.125f;
      float v1 = s1[r] * 0.125f;
      float tm = fmaxf(v0, v1);
#pragma unroll
      for (int off = 8; off > 0; off >>= 1) tm = fmaxf(tm, __shfl_xor(tm, off, 16));
      float mnew = fmaxf(m_run[r], tm);
      float a = __expf(m_run[r] - mnew);
      m_run[r] = mnew;
      float p0 = __expf(v0 - mnew);
      float p1 = __expf(v1 - mnew);
      float rs = p0 + p1;
#pragma unroll
      for (int off = 8; off > 0; off >>= 1) rs += __shfl_xor(rs, off, 16);
      l_run[r] = l_run[r] * a + rs;
      al[r] = a;
      s0[r] = p0; s1[r] = p1;
    }
#pragma unroll
    for (int dt = 0; dt < 4; dt++)
#pragma unroll
      for (int r = 0; r < 4; r++) o_acc[dt][r] *= al[r];

    // ---- P: C-layout -> LDS -> A-layout (wave-local; DS is in-order/wave) ----
#pragma unroll
    for (int r = 0; r < 4; r++) {
      Ps[wv][(quad * 4 + r) * 32 + l16]      = (__bf16)s0[r];
      Ps[wv][(quad * 4 + r) * 32 + 16 + l16] = (__bf16)s1[r];
    }
    asm volatile("s_waitcnt lgkmcnt(0)" ::: "memory");
    bf16x8 pa = *(const bf16x8*)(&Ps[wv][l16 * 32 + quad * 8]);

    // ---- O += P V, V fragments from transposed LDS (vector b64 reads) ----
#pragma unroll
    for (int dt = 0; dt < 4; dt++) {
      const __bf16* vp = &Vt[(dt * 16 + l16) * 44 + quad * 8];
      bf16x4 vlo = *(const bf16x4*)(vp);
      bf16x4 vhi = *(const bf16x4*)(vp + 4);
      bf16x8 vb = __builtin_shufflevector(vlo, vhi, 0, 1, 2, 3, 4, 5, 6, 7);
      o_acc[dt] = __builtin_amdgcn_mfma_f32_16x16x32_bf16(pa, vb, o_acc[dt], 0, 0, 0);
    }
    __syncthreads();   // all reads done before next staging overwrite
  }

  // epilogue: ao[b][hw=q][hd*64+d] bf16
#pragma unroll
  for (int dt = 0; dt < 4; dt++) {
#pragma unroll
    for (int r = 0; r < 4; r++) {
      float val = o_acc[dt][r] / l_run[r];
      int qg = q0 + quad * 4 + r;
      ao[(size_t)(b * HW_ + qg) * C_ + hd * D_ + dt * 16 + l16] = (__bf16)val;
    }
  }
}

// ---------------------------------------------------------------------------
extern "C" void kernel_launch(void* const* d_in, const int* in_sizes, int n_in,
                              void* d_out, int out_size, void* d_ws, size_t ws_size,
                              hipStream_t stream) {
  const float* x      = (const float*)d_in[0];
  const float* gn_w   = (const float*)d_in[1];
  const float* gn_b   = (const float*)d_in[2];
  const float* qkv_w  = (const float*)d_in[3];
  const float* qkv_b  = (const float*)d_in[4];
  const float* proj_w = (const float*)d_in[5];
  const float* proj_b = (const float*)d_in[6];
  float* out = (float*)d_out;

  char* ws = (char*)d_ws;
  __bf16* h   = (__bf16*)(ws);
  __bf16* qwb = (__bf16*)(ws + 8388608);
  __bf16* pwb = (__bf16*)(ws + 8388608 + 1572864);
  __bf16* yq  = (__bf16*)(ws + 8388608 + 1572864 + 524288);
  __bf16* ao  = (__bf16*)(ws + 8388608 + 1572864 + 524288 + 25165824);

  k_gn  <<<B_ * G_, 256, 0, stream>>>(x, gn_w, gn_b, h);
  k_cvt <<<(O3_ * C_ + 255) / 256, 256, 0, stream>>>(qkv_w, proj_w, qwb, pwb);
  k_qkv <<<dim3(M_TOT / 128, O3_ / 128, 1), 256, 0, stream>>>(h, qwb, qkv_b, yq);
  k_attn<<<dim3(16, HEADS_, B_), 256, 0, stream>>>(yq, ao);
  k_proj<<<dim3(M_TOT / 128, C_ / 128, 1), 256, 0, stream>>>(ao, pwb, proj_b, x, out);
  (void)in_sizes; (void)n_in; (void)out_size; (void)ws_size;
}